// Round 9
// baseline (93.005 us; speedup 1.0000x reference)
//
#include <hip/hip_runtime.h>

#define B_ 32
#define N_ 1024
// dk = 128^-0.5 / 1024
#define DK_CONST 8.631674575031098e-05f
#define NM1 1023.0f
#define POISON_U 0xAAAAAAAAu

typedef unsigned short u16;
typedef unsigned int u32;
typedef __attribute__((ext_vector_type(8))) short short8;
typedef __attribute__((ext_vector_type(4))) float floatx4;

__device__ __forceinline__ u16 f2b(float x) {
    union { float f; u32 u; } v; v.f = x;
    u32 u = v.u;
    return (u16)((u + 0x7FFFu + ((u >> 16) & 1u)) >> 16);
}
__device__ __forceinline__ float b2f(u16 h) {
    union { u32 u; float f; } v; v.u = ((u32)h) << 16;
    return v.f;
}
__device__ __forceinline__ void pubf(float* p, float x) {
    union { float f; u32 u; } c; c.f = x;
    __hip_atomic_store((u32*)p, c.u, __ATOMIC_RELAXED, __HIP_MEMORY_SCOPE_AGENT);
}
__device__ __forceinline__ u32 ald(const float* p) {
    return __hip_atomic_load((const u32*)p, __ATOMIC_RELAXED, __HIP_MEMORY_SCOPE_AGENT);
}
__device__ __forceinline__ float u2f(u32 u) { union { u32 u_; float f; } c; c.u_ = u; return c.f; }

// Single fused kernel: 256 blocks == 256 CUs, 1 block/CU (co-residency proven R7/R8).
// Cross-block sync: 0xAA-poison sentinel spins on relaxed agent-scope atomics.
// XCD swizzle: tile = (blockIdx&31)*8 + (blockIdx>>5) puts a batch's 8 peer
// blocks at blockIdx = b, b+32, ..., b+224 — same residue mod 8 — so under
// round-robin block->XCD dispatch all spin traffic is XCD-local L2.
// Correctness does NOT depend on the mapping (agent-scope atomics).
__global__ __launch_bounds__(256, 1) void mega(
    const float* __restrict__ aq, const float* __restrict__ mask,
    const float* __restrict__ Wq, const float* __restrict__ bq,
    const float* __restrict__ Wk, const float* __restrict__ bk,
    const float* __restrict__ Wv, const float* __restrict__ bv,
    float* __restrict__ colsumPart, float* __restrict__ ssqPart,
    float* __restrict__ aggG, float* __restrict__ ctxPart,
    float* __restrict__ attnOut, float* __restrict__ ctxOut)
{
    __shared__ __align__(16) u16 aqT[128][136];      // bf16 aq tile, persistent all phases
    __shared__ __align__(16) char wbuf[69632];       // wA(Wk bf16)+wB(Wq bf16->Mt) -> later Wv fp32
    __shared__ __align__(16) char scratch[8704];     // cspart -> el ; accs ; pvec
    __shared__ float qpart[2][128];
    __shared__ float Ss[128], bq_s[128], bk_s[128], wc_s[128], w2_s[128];
    __shared__ float red[256];
    __shared__ float shv[4];                         // [0]=invn, [1]=bqbk

    u16 (*wA)[136]  = (u16(*)[136])wbuf;             // Wk rows bf16 (A of Mt-GEMM)
    u16 (*wB)[136]  = (u16(*)[136])(wbuf + 34816);   // Wq rows bf16 (B of Mt-GEMM) -> mtS
    u16 (*mtS)[136] = wB;
    float (*wv)[132] = (float(*)[132])wbuf;          // Wv fp32, overlays wA+wB after main GEMM
    float (*cspart)[4] = (float(*)[4])scratch;       // phase 1 only
    float* el   = (float*)scratch;                   // el[1024] after cspart dead
    float* accs = (float*)(scratch + 4096);          // [2][128]
    float* pvec = (float*)(scratch + 5120);          // [128]

    int t = threadIdx.x;
    // XCD-local batch clustering (see header comment)
    int tile = ((blockIdx.x & 31) << 3) | (blockIdx.x >> 5);
    int b = tile >> 3;
    int s = tile & 7;

    // ========== P1: stage aq tile (bf16) + colsum partial; stage Wk/Wq rows bf16 ==========
    if (t < 128) { bq_s[t] = bq[t]; bk_s[t] = bk[t]; wc_s[t] = 0.f; }
    const float4* aq4 = (const float4*)(aq + (size_t)tile * 16384);
    float c0 = 0.f, c1 = 0.f, c2 = 0.f, c3 = 0.f;
    for (int j = 0; j < 16; ++j) {
        int idx = t + 256 * j;
        int row = idx >> 5;
        int c4  = idx & 31;
        float4 v = aq4[idx];
        c0 += v.x; c1 += v.y; c2 += v.z; c3 += v.w;
        ushort4 bb;
        bb.x = f2b(v.x); bb.y = f2b(v.y); bb.z = f2b(v.z); bb.w = f2b(v.w);
        *((ushort4*)&aqT[row][c4 * 4]) = bb;
    }
    cspart[t][0] = c0; cspart[t][1] = c1; cspart[t][2] = c2; cspart[t][3] = c3;
    {
        const float4* wk4 = (const float4*)Wk;
        const float4* wq4 = (const float4*)Wq;
        for (int j = 0; j < 16; ++j) {
            int idx = t + 256 * j;
            int row = idx >> 5;
            int c4  = idx & 31;
            float4 a = wk4[idx];
            ushort4 ba;
            ba.x = f2b(a.x); ba.y = f2b(a.y); ba.z = f2b(a.z); ba.w = f2b(a.w);
            *((ushort4*)&wA[row][c4 * 4]) = ba;
            float4 q = wq4[idx];
            ushort4 bqv;
            bqv.x = f2b(q.x); bqv.y = f2b(q.y); bqv.z = f2b(q.z); bqv.w = f2b(q.w);
            *((ushort4*)&wB[row][c4 * 4]) = bqv;
        }
    }
    __syncthreads();
    if (t < 128) {
        int c4i = t >> 2, comp = t & 3;
        float sum = 0.f;
        for (int h = 0; h < 8; ++h) sum += cspart[h * 32 + c4i][comp];
        pubf(&colsumPart[tile * 128 + t], sum);      // publish ASAP for batch peers
    }
    red[t] = (t < 128) ? (fabsf(bq_s[t]) + fabsf(bk_s[t])) : 0.f;
    __syncthreads();
    for (int st = 128; st > 0; st >>= 1) { if (t < st) red[t] += red[t + st]; __syncthreads(); }
    float nb = red[0];
    __syncthreads();

    // ========== P2: Mt = Wk * Wq^T via MFMA (both operands row-major, no transpose) ==========
    int w = t >> 6;
    int lane = t & 63;
    int wr   = (w >> 1) * 64;
    int wcol = (w & 1) * 64;
    int lm = lane & 15;
    int lq = lane >> 4;

    floatx4 accM[4][4];
    for (int i = 0; i < 4; ++i)
        for (int j = 0; j < 4; ++j)
            accM[i][j] = (floatx4){0.f, 0.f, 0.f, 0.f};
    for (int ks = 0; ks < 4; ++ks) {
        int k0 = ks * 32 + lq * 8;
        short8 afr[4], bfr[4];
        for (int i = 0; i < 4; ++i) {
            afr[i] = *(const short8*)&wA[wr + i * 16 + lm][k0];
            bfr[i] = *(const short8*)&wB[wcol + i * 16 + lm][k0];
        }
        for (int i = 0; i < 4; ++i)
            for (int j = 0; j < 4; ++j)
                accM[i][j] = __builtin_amdgcn_mfma_f32_16x16x32_bf16(afr[i], bfr[j], accM[i][j], 0, 0, 0);
    }
    // bias vectors (generic path; biases are zero here so this is skipped block-uniformly)
    if (nb != 0.f) {
        if (t < 128) {
            float w1 = 0.f, w2 = 0.f;
            for (int d = 0; d < 128; ++d) {
                w1 += b2f(wB[t][d]) * bk_s[d];   // Wq.bk
                w2 += b2f(wA[t][d]) * bq_s[d];   // Wk.bq
            }
            wc_s[t] = NM1 * w1 - w2;
            w2_s[t] = w2;
        }
        red[t] = (t < 128) ? bq_s[t] * bk_s[t] : 0.f;
        __syncthreads();
        for (int st = 128; st > 0; st >>= 1) { if (t < st) red[t] += red[t + st]; __syncthreads(); }
        if (t == 0) shv[1] = red[0];
        __syncthreads();
    }
    __syncthreads();                                  // all wB fragment reads done
    // scatter Mt (C-layout) into mtS[g][f] bf16 (~2-way conflicts: free)
    for (int gi = 0; gi < 4; ++gi)
        for (int fj = 0; fj < 4; ++fj)
            for (int r = 0; r < 4; ++r)
                mtS[wr + gi * 16 + lq * 4 + r][wcol + fj * 16 + lm] = f2b(accM[gi][fj][r]);
    __syncthreads();

    // ========== P3: main MFMA T = Aq * M ==========
    floatx4 acc[4][4];
    for (int i = 0; i < 4; ++i)
        for (int j = 0; j < 4; ++j)
            acc[i][j] = (floatx4){0.f, 0.f, 0.f, 0.f};
    for (int ks = 0; ks < 4; ++ks) {
        int k0 = ks * 32 + lq * 8;
        short8 afr[4], mfr[4];
        for (int i = 0; i < 4; ++i) {
            afr[i] = *(const short8*)&aqT[wr + i * 16 + lm][k0];
            mfr[i] = *(const short8*)&mtS[wcol + i * 16 + lm][k0];
        }
        for (int i = 0; i < 4; ++i)
            for (int j = 0; j < 4; ++j)
                acc[i][j] = __builtin_amdgcn_mfma_f32_16x16x32_bf16(afr[i], mfr[j], acc[i][j], 0, 0, 0);
    }

    // ========== P4: spin colsum -> Ss (hidden behind MFMA issue above; XCD-local) ==========
    if (t < 128) {
        u32 raw[8];
        #pragma unroll
        for (int h = 0; h < 8; ++h) raw[h] = ald(&colsumPart[(b * 8 + h) * 128 + t]);
        float ssv = 0.f;
        #pragma unroll
        for (int h = 0; h < 8; ++h) {
            while (raw[h] == POISON_U) {
                __builtin_amdgcn_s_sleep(1);
                raw[h] = ald(&colsumPart[(b * 8 + h) * 128 + t]);
            }
            ssv += u2f(raw[h]);
        }
        Ss[t] = ssv;
    }
    __syncthreads();
    float Cbv = 0.f;
    if (nb != 0.f) {
        red[t] = (t < 128) ? Ss[t] * w2_s[t] : 0.f;
        __syncthreads();
        for (int st = 128; st > 0; st >>= 1) { if (t < st) red[t] += red[t + st]; __syncthreads(); }
        Cbv = red[0] + NM1 * shv[1];
        __syncthreads();
    }

    // ========== P5: epilogue -> agg + ssq publish ==========
    for (int mi = 0; mi < 4; ++mi) {
        for (int r = 0; r < 4; ++r) {
            int row = wr + mi * 16 + lq * 4 + r;
            float sx = 0.f;
            for (int nj = 0; nj < 4; ++nj) {
                int col = wcol + nj * 16 + lm;
                float av = b2f(aqT[row][col]);
                sx += acc[mi][nj][r] * (Ss[col] - av) + av * wc_s[col];
            }
            sx += __shfl_xor(sx, 1);
            sx += __shfl_xor(sx, 2);
            sx += __shfl_xor(sx, 4);
            sx += __shfl_xor(sx, 8);
            if (lm == 0) qpart[w & 1][row] = sx;
        }
    }
    __syncthreads();
    float av = 0.f;
    if (t < 128) {
        int atom = tile * 128 + t;
        av = mask[atom] * DK_CONST * (qpart[0][t] + qpart[1][t] + Cbv);
        pubf(&aggG[atom], av);
    }
    red[t] = av * av;
    __syncthreads();
    for (int st = 128; st > 0; st >>= 1) { if (t < st) red[t] += red[t + st]; __syncthreads(); }
    if (t == 0) pubf(&ssqPart[tile], red[0]);
    __syncthreads();

    // ========== P6: stage Wv (overlaps peer wait); spin ssq+agg -> softmax ==========
    {
        const float4* wv4 = (const float4*)Wv;
        for (int j = 0; j < 16; ++j) {
            int idx = t + 256 * j;
            int f  = idx >> 5;
            int d4 = (idx & 31) * 4;
            *((float4*)&wv[f][d4]) = wv4[idx];
        }
    }
    if (t < 8) {
        u32 raw = ald(&ssqPart[b * 8 + t]);
        while (raw == POISON_U) {
            __builtin_amdgcn_s_sleep(1);
            raw = ald(&ssqPart[b * 8 + t]);
        }
        red[t] = u2f(raw);
    }
    __syncthreads();
    if (t == 0) {
        float ssum = 0.f;
        for (int h = 0; h < 8; ++h) ssum += red[h];
        shv[0] = 1.0f / sqrtf(ssum);
    }
    __syncthreads();
    float invn = shv[0];
    u32 raga[4];
    #pragma unroll
    for (int j = 0; j < 4; ++j) raga[j] = ald(&aggG[b * 1024 + j * 256 + t]);
    float epart = 0.f;
    #pragma unroll
    for (int j = 0; j < 4; ++j) {
        int i = j * 256 + t;
        while (raga[j] == POISON_U) {
            __builtin_amdgcn_s_sleep(1);
            raga[j] = ald(&aggG[b * 1024 + i]);
        }
        float m = mask[b * 1024 + i];
        float e = (m > 0.5f) ? expf(u2f(raga[j]) * invn) : 0.f;   // |agg*invn| <= 1 (C-S)
        el[i] = e;
        epart += e;
    }
    red[t] = epart;
    __syncthreads();
    for (int st = 128; st > 0; st >>= 1) { if (t < st) red[t] += red[t + st]; __syncthreads(); }
    float invE = 1.0f / red[0];
    if (t < 128) attnOut[tile * 128 + t] = el[s * 128 + t] * invE;

    // ========== P7: ctx partial from resident bf16 LDS tile; project Wv ==========
    {
        int f = t & 127, hh = t >> 7;
        float acc2 = 0.f;
        for (int r = hh; r < 128; r += 2) acc2 += el[s * 128 + r] * b2f(aqT[r][f]);
        accs[hh * 128 + f] = acc2;
    }
    __syncthreads();
    if (t < 128) pvec[t] = accs[t] + accs[128 + t];
    __syncthreads();
    if (t < 128) {
        float c = 0.f;
        for (int f = 0; f < 128; ++f) c += pvec[f] * wv[f][t];
        pubf(&ctxPart[tile * 128 + t], c * invE);
    }

    // ========== P8: batch finalizers (s==0) ==========
    if (s == 0 && t < 128) {
        u32 raw[8];
        #pragma unroll
        for (int h = 0; h < 8; ++h) raw[h] = ald(&ctxPart[(b * 8 + h) * 128 + t]);
        float c = 0.f;
        #pragma unroll
        for (int h = 0; h < 8; ++h) {
            while (raw[h] == POISON_U) {
                __builtin_amdgcn_s_sleep(1);
                raw[h] = ald(&ctxPart[(b * 8 + h) * 128 + t]);
            }
            c += u2f(raw[h]);
        }
        ctxOut[b * 128 + t] = c + bv[t];    // sum(mask*attn) == 1 exactly
    }
}

extern "C" void kernel_launch(void* const* d_in, const int* in_sizes, int n_in,
                              void* d_out, int out_size, void* d_ws, size_t ws_size,
                              hipStream_t stream) {
    const float* aq   = (const float*)d_in[0];   // [B,N,F]
    const float* mask = (const float*)d_in[1];   // [B,N,1]
    const float* Wq   = (const float*)d_in[2];
    const float* bq   = (const float*)d_in[3];
    const float* Wk   = (const float*)d_in[4];
    const float* bk   = (const float*)d_in[5];
    const float* Wv   = (const float*)d_in[6];
    const float* bv   = (const float*)d_in[7];

    float* out_attn = (float*)d_out;             // [B,N,1] = 32768
    float* out_ctx  = out_attn + B_ * N_;        // [B,D]   = 4096

    float* wsf        = (float*)d_ws;
    float* colsumPart = wsf;                     // 32768 floats (poison = not-ready sentinel)
    float* ssqPart    = wsf + 32768;             // 256
    float* aggG       = wsf + 33024;             // 32768
    float* ctxPart    = wsf + 65792;             // 32768

    mega<<<256, 256, 0, stream>>>(aq, mask, Wq, bq, Wk, bk, Wv, bv,
                                  colsumPart, ssqPart, aggG, ctxPart,
                                  out_attn, out_ctx);
}